// Round 1
// 5589.285 us; speedup vs baseline: 1.1237x; 1.1237x over previous
//
#include <hip/hip_runtime.h>
#include <math.h>

// T=64, B=128, H=256, C=256, K=8, L=3.
// NEW STRUCTURE (this round): 2 blocks per sample ("pair"), 256 blocks total so
// all 256 CUs are active (was 128 blocks -> OccupancyPercent 11.8%).
// Pair split is by UNIT/CLASS half: block owns 128 of 256 LSTM units and 128 of
// 256 classes. With XCD mapping half = (blockIdx%8)>=4 (round-robin dispatch
// assumption, perf-only), each XCD's L2 holds only its half's weights (~3.6MB
// vs 4MB L2; the old 7.6MB set thrashed L2).
// Cross-block exchange (4 x 4KB per step: logits, h0, h1, h2) uses RELAXED
// agent-scope atomics (sc1 -> MALL-coherent). NO acquire/release fences: those
// emit buffer_inv/wbl2 which would evict the L2-resident weights. Ordering:
// writer: data atomics -> __syncthreads (drains vmcnt -> data at MALL) ->
// tid0 posts monotonic flag; reader: tid0 polls flag -> __syncthreads ->
// atomic data loads. Flags zeroed by k_prep each launch (stream-ordered),
// so graph replay is safe; no epoch logic needed.
// h-exchanges are latency-hidden: each layer runs its RECURRENT gemm (operands
// already resident) before polling for the partner's previous-layer h.
// Both blocks run softmax/top-k redundantly on bit-identical logits ->
// identical beam decisions (deterministic), no extra exchange.
static constexpr size_t O_EMBW  = 0;         // [256 cls][1024 (u*4+g)]  emb@Wih0^T + b0
static constexpr size_t O_WPT   = 262144;    // [256 k][256 c]
static constexpr size_t O_WIHT  = 327680;    // [3][256 k][1024 (u*4+g)]
static constexpr size_t O_WHHT  = 1114112;   // [3][256 k][1024 (u*4+g)]
static constexpr size_t O_BIASC = 1900544;   // [3][256 u][4 g]  bih+bhh
static constexpr size_t O_XCHG  = 1903616;   // [128 smp][2 half][4 phase][1024] floats
static constexpr size_t O_FLAGS = 2952192;   // 1024 uint32: [smp][4 phase][2 half]
// total 2953216 floats ≈ 11.8 MB

typedef float f2 __attribute__((ext_vector_type(2)));
__device__ __forceinline__ f2 fma2(f2 a, f2 b, f2 c){ return __builtin_elementwise_fma(a,b,c); }
__device__ __forceinline__ float sigf(float x){ return 1.0f/(1.0f + expf(-x)); }

__device__ __forceinline__ void astoref(float* p, float v){
  __hip_atomic_store(p, v, __ATOMIC_RELAXED, __HIP_MEMORY_SCOPE_AGENT);
}
__device__ __forceinline__ float aloadf(const float* p){
  return __hip_atomic_load((float*)p, __ATOMIC_RELAXED, __HIP_MEMORY_SCOPE_AGENT);
}

// ---------------- one-time prep: transposes + combined biases + flag reset ----
__global__ __launch_bounds__(256) void k_prep(
    const float* __restrict__ Wih, const float* __restrict__ Whh,
    const float* __restrict__ Wp,  const float* __restrict__ bih,
    const float* __restrict__ bhh,
    float* __restrict__ wihT, float* __restrict__ whhT,
    float* __restrict__ WpT, float* __restrict__ biasC,
    float* __restrict__ flagsF)
{
  const int NT = 786432;
  const int TOTAL = 2*NT + 65536 + 3072 + 1024;
  int stride = gridDim.x * blockDim.x;
  for (int i = blockIdx.x*blockDim.x + threadIdx.x; i < TOTAL; i += stride){
    if (i < NT){
      int l = i / 262144, r = i % 262144;      // r = row*256 + k
      int row = r >> 8, k = r & 255;
      int g = row >> 8, uu = row & 255;
      wihT[(size_t)l*262144 + (k<<10) + (uu<<2) + g] = Wih[i];
    } else if (i < 2*NT){
      int j = i - NT;
      int l = j / 262144, r = j % 262144;
      int row = r >> 8, k = r & 255;
      int g = row >> 8, uu = row & 255;
      whhT[(size_t)l*262144 + (k<<10) + (uu<<2) + g] = Whh[j];
    } else if (i < 2*NT + 65536){
      int j = i - 2*NT; int c = j >> 8, k = j & 255;
      WpT[(k<<8) + c] = Wp[j];
    } else if (i < 2*NT + 65536 + 3072){
      int j = i - 2*NT - 65536;          // [3][256][4]
      int l = j >> 10; int cg = j & 1023, uu = cg >> 2, g = cg & 3;
      biasC[j] = bih[l*1024 + g*256 + uu] + bhh[l*1024 + g*256 + uu];
    } else {
      flagsF[i - (2*NT + 65536 + 3072)] = 0.0f;   // zero sync flags every launch
    }
  }
}

// ------------- one-time: embW[cls][u*4+g] = emb@Wih0^T + bih0 + bhh0 ---------
__global__ __launch_bounds__(256) void k_embW(
    const float* __restrict__ emb, const float* __restrict__ wih0T,
    const float* __restrict__ bih, const float* __restrict__ bhh,
    float* __restrict__ embW)
{
  const int cls = blockIdx.x, uu = threadIdx.x;
  const float* er = emb + cls*256;
  float a0=0.f,a1=0.f,a2=0.f,a3=0.f;
  for (int k=0;k<256;k++){
    float ev = er[k];
    float4 w = *(const float4*)&wih0T[k*1024 + uu*4];
    a0 = fmaf(ev, w.x, a0); a1 = fmaf(ev, w.y, a1);
    a2 = fmaf(ev, w.z, a2); a3 = fmaf(ev, w.w, a3);
  }
  a0 += bih[uu]       + bhh[uu];
  a1 += bih[256+uu]   + bhh[256+uu];
  a2 += bih[512+uu]   + bhh[512+uu];
  a3 += bih[768+uu]   + bhh[768+uu];
  *(float4*)&embW[cls*1024 + uu*4] = make_float4(a0,a1,a2,a3);
}

// ---------------- decode: 2 blocks = 1 sample, 512 threads each --------------
__global__
__attribute__((amdgpu_flat_work_group_size(512,512)))
void k_decode(
    const float* __restrict__ x,      // [64][128][256]
    const float* __restrict__ WpT,    // [256 k][256 c]
    const float* __restrict__ wihT,   // [3][256 k][1024]
    const float* __restrict__ whhT,   // [3][256 k][1024]
    const float* __restrict__ biasC,  // [3][256 u][4 g]
    const float* __restrict__ embW,   // [256 cls][1024]
    const float* __restrict__ bp,     // [256]
    float* __restrict__ xchg,         // [128][2][4][1024]
    unsigned* __restrict__ flags,     // [128][4][2]
    float* __restrict__ out)
{
  __shared__ float hS[3*2048];   // h[l][row][unit 0..255] FULL width   24 KB
  __shared__ float cS[1024];     // staged c_old[row][own-unit 0..127]   4 KB
  __shared__ float st[2048];     // state[row][unit] FULL width          8 KB
  __shared__ float jnt[4096];    // logits/joint + partial exchange     16 KB
  __shared__ float pfx[8];
  __shared__ float red[8];  __shared__ int redi[8];
  __shared__ float sVal[8]; __shared__ int sPrev[8], sCls[8];
  __shared__ short prevH[512], clsH[512];

  const int tid  = threadIdx.x;
  const int bid  = blockIdx.x;
  const int half = (bid & 7) >> 2;          // 0: XCD 0-3, 1: XCD 4-7 (heuristic)
  const int oh   = half ^ 1;
  const int smp  = ((bid >> 3) << 2) | (bid & 3);   // sample 0..127, bijective
  const int u    = tid & 127;               // local unit / class col
  const int kh   = (tid >> 7) & 1;          // split-K half
  const int rh   = tid >> 8;                // row-quad
  const int U    = (half << 7) | u;         // global unit / class
  const int or0  = rh*4 + kh*2;             // owned beam rows
  const int or1  = or0 + 1;
  const int wv   = tid >> 6, lane = tid & 63;

  float* xbase = xchg + (size_t)smp*8192;
  unsigned* fme = flags + smp*8 + half;     // use fme[p*2]
  unsigned* fpr = flags + smp*8 + oh;

  float creg[3][2];                         // c for owned rows or0/or1, unit u
  const float bpc = bp[U];

  // ---- init: x0 into jnt[2048..2303]; st = x0 broadcast; prefix ----
  if (tid < 64) *(float4*)&jnt[2048 + tid*4] = *(const float4*)&x[(size_t)smp*256 + tid*4];
  if (tid < 8)  pfx[tid] = (tid==0) ? 0.0f : -1e30f;
  __syncthreads();
  *(float4*)&st[tid*4] = *(const float4*)&jnt[2048 + (tid&63)*4];

  // ---- init LSTM from zero state (M=1); per layer: compute own half, exchange
  for (int l=0; l<3; l++){
    if (tid < 128){
      const float* Wg = wihT + (size_t)l*262144;
      float a0=0.f,a1=0.f,a2=0.f,a3=0.f;
      for (int kc=0; kc<256; kc+=4){
        float4 a4 = *(const float4*)&jnt[2048+kc];
        float4 w0 = *(const float4*)&Wg[(size_t)(kc+0)*1024 + U*4];
        float4 w1 = *(const float4*)&Wg[(size_t)(kc+1)*1024 + U*4];
        float4 w2 = *(const float4*)&Wg[(size_t)(kc+2)*1024 + U*4];
        float4 w3 = *(const float4*)&Wg[(size_t)(kc+3)*1024 + U*4];
        a0=fmaf(a4.x,w0.x,a0); a0=fmaf(a4.y,w1.x,a0); a0=fmaf(a4.z,w2.x,a0); a0=fmaf(a4.w,w3.x,a0);
        a1=fmaf(a4.x,w0.y,a1); a1=fmaf(a4.y,w1.y,a1); a1=fmaf(a4.z,w2.y,a1); a1=fmaf(a4.w,w3.y,a1);
        a2=fmaf(a4.x,w0.z,a2); a2=fmaf(a4.y,w1.z,a2); a2=fmaf(a4.z,w2.z,a2); a2=fmaf(a4.w,w3.z,a2);
        a3=fmaf(a4.x,w0.w,a3); a3=fmaf(a4.y,w1.w,a3); a3=fmaf(a4.z,w2.w,a3); a3=fmaf(a4.w,w3.w,a3);
      }
      float4 bs = *(const float4*)&biasC[(l*256+U)*4];
      float gi=a0+bs.x, gg=a2+bs.z, go=a3+bs.w;  // c_old=0
      float cn = sigf(gi)*tanhf(gg);
      float hn = sigf(go)*tanhf(cn);
      jnt[tid] = hn; jnt[128+tid] = cn;
    }
    __syncthreads();
    {
      float* xm = xbase + (half*4 + (l+1))*1024;
      float hv = jnt[u], cv = jnt[128+u];
      creg[l][0] = cv; creg[l][1] = cv;
      hS[l*2048 + or0*256 + U] = hv;
      hS[l*2048 + or1*256 + U] = hv;
      astoref(&xm[or0*128 + u], hv);
      astoref(&xm[or1*128 + u], hv);
    }
    __syncthreads();   // drains vmcnt: exchange data at MALL
    if (tid==0){
      __hip_atomic_store(&fme[(l+1)*2], 1u, __ATOMIC_RELAXED, __HIP_MEMORY_SCOPE_AGENT);
      while (__hip_atomic_load(&fpr[(l+1)*2], __ATOMIC_RELAXED, __HIP_MEMORY_SCOPE_AGENT) < 1u)
        __builtin_amdgcn_s_sleep(2);
    }
    __syncthreads();
    {
      const float* xr = xbase + (oh*4 + (l+1))*1024;
      int r = tid>>6, u2 = (tid&63)*2;
      float v0 = aloadf(&xr[r*128+u2]);
      float v1 = aloadf(&xr[r*128+u2+1]);
      hS[l*2048 + r*256 + (oh<<7)+u2]   = v0;
      hS[l*2048 + r*256 + (oh<<7)+u2+1] = v1;
      if (l<2 && r==0){ jnt[2048+(oh<<7)+u2] = v0; jnt[2048+(oh<<7)+u2+1] = v1; }
    }
    if (l<2 && tid<128) jnt[2048 + U] = jnt[tid];   // own half of next input row
    __syncthreads();
  }

  // split-K GEMM: 4 rows x 4 gate-cols of unit U over this thread's 128 k's.
  // 2-stage rolling W prefetch (32 VGPR). acc2: row i -> acc2[i*2]={g_i,g_f},
  // acc2[i*2+1]={g_g,g_o}.
  auto gemm4 = [&](const float* hbaseK, const int* ro, const float* WgK, f2* acc2){
    const float* Wr = WgK + (U<<2);
    float4 wst[2][4];
    #pragma unroll
    for (int s=0; s<2; s++){
      const float* Wn = Wr + (size_t)(s*4)*1024;
      wst[s][0]=*(const float4*)&Wn[0];    wst[s][1]=*(const float4*)&Wn[1024];
      wst[s][2]=*(const float4*)&Wn[2048]; wst[s][3]=*(const float4*)&Wn[3072];
    }
    auto macblk = [&](const float4 wk[4], const float4 a[4]){
      #pragma unroll
      for (int kk=0;kk<4;kk++){
        f2 wlo = {wk[kk].x, wk[kk].y};
        f2 whi = {wk[kk].z, wk[kk].w};
        const float av4[4] = {
          kk==0?a[0].x:(kk==1?a[0].y:(kk==2?a[0].z:a[0].w)),
          kk==0?a[1].x:(kk==1?a[1].y:(kk==2?a[1].z:a[1].w)),
          kk==0?a[2].x:(kk==1?a[2].y:(kk==2?a[2].z:a[2].w)),
          kk==0?a[3].x:(kk==1?a[3].y:(kk==2?a[3].z:a[3].w))};
        #pragma unroll
        for (int i=0;i<4;i++){
          f2 av = {av4[i], av4[i]};
          acc2[i*2+0] = fma2(av, wlo, acc2[i*2+0]);
          acc2[i*2+1] = fma2(av, whi, acc2[i*2+1]);
        }
      }
    };
    #pragma unroll 1
    for (int kc=0; kc<120; kc+=8){
      #pragma unroll
      for (int s=0; s<2; s++){
        const int kcur = kc + s*4;
        const float4 wk[4] = {wst[s][0], wst[s][1], wst[s][2], wst[s][3]};
        const float* Wn = Wr + (size_t)(kcur+8)*1024;
        wst[s][0]=*(const float4*)&Wn[0];    wst[s][1]=*(const float4*)&Wn[1024];
        wst[s][2]=*(const float4*)&Wn[2048]; wst[s][3]=*(const float4*)&Wn[3072];
        float4 a[4];
        #pragma unroll
        for (int i=0;i<4;i++) a[i] = *(const float4*)&hbaseK[ro[i] + kcur];
        macblk(wk, a);
      }
    }
    #pragma unroll
    for (int s=0; s<2; s++){
      const int kcur = 120 + s*4;
      const float4 wk[4] = {wst[s][0], wst[s][1], wst[s][2], wst[s][3]};
      float4 a[4];
      #pragma unroll
      for (int i=0;i<4;i++) a[i] = *(const float4*)&hbaseK[ro[i] + kcur];
      macblk(wk, a);
    }
  };

  // ---------------- 64 decode steps ----------------
  for (int t=0; t<64; t++){
    // ---- phase3 poll: partner h[2] (+ partner half of st for t>0) ----
    if (tid==0){
      unsigned want = (unsigned)(t+1);
      while (__hip_atomic_load(&fpr[3*2], __ATOMIC_RELAXED, __HIP_MEMORY_SCOPE_AGENT) < want)
        __builtin_amdgcn_s_sleep(2);
    }
    __syncthreads();
    {
      const float* xr = xbase + (oh*4 + 3)*1024;
      int r = tid>>6, u2 = (tid&63)*2;
      float v0 = aloadf(&xr[r*128+u2]);
      float v1 = aloadf(&xr[r*128+u2+1]);
      hS[2*2048 + r*256 + (oh<<7)+u2]   = v0;
      hS[2*2048 + r*256 + (oh<<7)+u2+1] = v1;
      if (t > 0){
        f2 xv = *(const f2*)&x[(size_t)t*32768 + smp*256 + (oh<<7)+u2];
        st[r*256 + (oh<<7)+u2]   = v0 + xv.x;
        st[r*256 + (oh<<7)+u2+1] = v1 + xv.y;
      }
    }
    __syncthreads();   // st/hS[2] complete

    // ---- proj: rows rq*2,rq*2+1, own class col U; 4-stage scalar prefetch ----
    {
      const int rq = tid >> 7;                 // 0..3
      const float* A0 = st + (rq*2)*256;
      const float* A1 = st + (rq*2+1)*256;
      const float* Wc = WpT + U;
      f2 q01 = {0.f,0.f};
      float wstp[4][4];
      #pragma unroll
      for (int s=0;s<4;s++){
        #pragma unroll
        for (int q=0;q<4;q++) wstp[s][q] = Wc[(s*4+q)*256];
      }
      #pragma unroll 1
      for (int kc=0; kc<240; kc+=16){
        #pragma unroll
        for (int s=0;s<4;s++){
          const int kcur = kc + s*4;
          float w0=wstp[s][0], w1=wstp[s][1], w2=wstp[s][2], w3=wstp[s][3];
          #pragma unroll
          for (int q=0;q<4;q++) wstp[s][q] = Wc[(kcur+16+q)*256];
          float4 a0 = *(const float4*)&A0[kcur];
          float4 a1 = *(const float4*)&A1[kcur];
          q01 = fma2((f2){a0.x,a1.x}, (f2){w0,w0}, q01);
          q01 = fma2((f2){a0.y,a1.y}, (f2){w1,w1}, q01);
          q01 = fma2((f2){a0.z,a1.z}, (f2){w2,w2}, q01);
          q01 = fma2((f2){a0.w,a1.w}, (f2){w3,w3}, q01);
        }
      }
      #pragma unroll
      for (int s=0;s<4;s++){
        const int kcur = 240 + s*4;
        float w0=wstp[s][0], w1=wstp[s][1], w2=wstp[s][2], w3=wstp[s][3];
        float4 a0 = *(const float4*)&A0[kcur];
        float4 a1 = *(const float4*)&A1[kcur];
        q01 = fma2((f2){a0.x,a1.x}, (f2){w0,w0}, q01);
        q01 = fma2((f2){a0.y,a1.y}, (f2){w1,w1}, q01);
        q01 = fma2((f2){a0.z,a1.z}, (f2){w2,w2}, q01);
        q01 = fma2((f2){a0.w,a1.w}, (f2){w3,w3}, q01);
      }
      float v0 = q01.x + bpc, v1 = q01.y + bpc;
      float* xm = xbase + (half*4 + 0)*1024;
      jnt[(rq*2)*256 + U]   = v0;
      jnt[(rq*2+1)*256 + U] = v1;
      astoref(&xm[(rq*2)*128 + u],   v0);
      astoref(&xm[(rq*2+1)*128 + u], v1);
    }
    __syncthreads();   // jnt own half visible; exchange data at MALL
    if (tid==0){
      __hip_atomic_store(&fme[0], (unsigned)(t+1), __ATOMIC_RELAXED, __HIP_MEMORY_SCOPE_AGENT);
      while (__hip_atomic_load(&fpr[0], __ATOMIC_RELAXED, __HIP_MEMORY_SCOPE_AGENT) < (unsigned)(t+1))
        __builtin_amdgcn_s_sleep(2);
    }
    __syncthreads();
    {
      const float* xr = xbase + (oh*4 + 0)*1024;
      int r = tid>>6, c2 = (tid&63)*2;
      jnt[r*256 + (oh<<7) + c2]   = aloadf(&xr[r*128+c2]);
      jnt[r*256 + (oh<<7) + c2+1] = aloadf(&xr[r*128+c2+1]);
    }
    __syncthreads();

    // ---- log-softmax + prefix: wave wv handles beam-row wv (redundant x2) ----
    {
      const int kb = wv;
      float4 v = *(const float4*)&jnt[kb*256 + lane*4];
      float m = fmaxf(fmaxf(v.x,v.y),fmaxf(v.z,v.w));
      for (int off=32;off;off>>=1) m = fmaxf(m, __shfl_down(m,off));
      m = __shfl(m, 0);
      double s = exp((double)v.x-(double)m)+exp((double)v.y-(double)m)
               + exp((double)v.z-(double)m)+exp((double)v.w-(double)m);
      for (int off=32;off;off>>=1) s += __shfl_down(s,off);
      s = __shfl(s, 0);
      double lse = log(s);
      float pf = pfx[kb];
      float4 o;
      o.x = (float)((double)v.x - (double)m - lse) + pf;
      o.y = (float)((double)v.y - (double)m - lse) + pf;
      o.z = (float)((double)v.z - (double)m - lse) + pf;
      o.w = (float)((double)v.w - (double)m - lse) + pf;
      *(float4*)&jnt[kb*256+lane*4] = o;
    }
    __syncthreads();

    // ---- top-8 of joint[2048]; stride-512 reads, (val, lowest-idx) ----
    for (int r=0;r<8;r++){
      float bv = -INFINITY; int bi = 0;
      #pragma unroll
      for (int i=0;i<4;i++){
        int idx = tid + 512*i; float vv = jnt[idx];
        if (vv > bv){ bv=vv; bi=idx; }
      }
      for (int off=32;off;off>>=1){
        float ov = __shfl_down(bv,off); int oi = __shfl_down(bi,off);
        if (ov>bv || (ov==bv && oi<bi)){ bv=ov; bi=oi; }
      }
      if (lane==0){ red[wv]=bv; redi[wv]=bi; }
      __syncthreads();
      if (tid==0){
        float BV=red[0]; int BI=redi[0];
        for (int j=1;j<8;j++) if (red[j]>BV || (red[j]==BV && redi[j]<BI)){BV=red[j];BI=redi[j];}
        sVal[r]=BV; sPrev[r]=BI>>8; sCls[r]=BI&255;
        jnt[BI] = -INFINITY;
      }
      __syncthreads();
    }
    if (tid<8){
      pfx[tid] = sVal[tid];
      prevH[t*8+tid] = (short)sPrev[tid];
      clsH[t*8+tid]  = (short)sCls[tid];
    }
    __syncthreads();

    int rog4[4], rod4[4];
    #pragma unroll
    for (int i=0;i<4;i++){ rog4[i] = sPrev[rh*4+i]*256; rod4[i] = (rh*4+i)*256; }
    const int clr0 = sCls[or0], clr1 = sCls[or1];
    const int pv0  = sPrev[or0], pv1 = sPrev[or1];

    // ---- 3 LSTM layers (unit-split across the pair, split-K within block) ----
    #pragma unroll 1
    for (int l=0; l<3; l++){
      cS[or0*128 + u] = creg[l][0];
      cS[or1*128 + u] = creg[l][1];
      __syncthreads();   // cS visible; hS stable; jnt free

      f2 acc2[8];
      #pragma unroll
      for (int i=0;i<8;i++) acc2[i] = (f2){0.f,0.f};
      // recurrent first (operands resident) -> hides the h[l-1] exchange poll
      gemm4(hS + l*2048 + (kh<<7), rog4,
            whhT + (size_t)l*262144 + ((size_t)(kh<<7))*1024, acc2);
      if (l > 0){
        if (tid==0){
          unsigned want = (unsigned)(t+2);
          while (__hip_atomic_load(&fpr[l*2], __ATOMIC_RELAXED, __HIP_MEMORY_SCOPE_AGENT) < want)
            __builtin_amdgcn_s_sleep(2);
        }
        __syncthreads();
        {
          const float* xr = xbase + (oh*4 + l)*1024;
          int r = tid>>6, u2 = (tid&63)*2;
          hS[(l-1)*2048 + r*256 + (oh<<7)+u2]   = aloadf(&xr[r*128+u2]);
          hS[(l-1)*2048 + r*256 + (oh<<7)+u2+1] = aloadf(&xr[r*128+u2+1]);
        }
        __syncthreads();
        gemm4(hS + (l-1)*2048 + (kh<<7), rod4,
              wihT + (size_t)l*262144 + ((size_t)(kh<<7))*1024, acc2);
      }
      __syncthreads();   // all gemm reads of hS done before epilogue writes

      // ship the 2 non-owned rows' partials to the partner-kh thread
      {
        int ptid = tid ^ 128;
        int s0 = (kh^1)*2;
        *(float4*)&jnt[ptid*8]   = make_float4(acc2[s0*2].x, acc2[s0*2].y,
                                               acc2[s0*2+1].x, acc2[s0*2+1].y);
        *(float4*)&jnt[ptid*8+4] = make_float4(acc2[(s0+1)*2].x, acc2[(s0+1)*2].y,
                                               acc2[(s0+1)*2+1].x, acc2[(s0+1)*2+1].y);
      }
      __syncthreads();
      {
        const int tn = (t < 63) ? (t+1) : 63;
        float4 p0 = *(const float4*)&jnt[tid*8];
        float4 p1 = *(const float4*)&jnt[tid*8+4];
        float4 b0, b1;
        if (l==0){
          b0 = *(const float4*)&embW[(size_t)clr0*1024 + U*4];
          b1 = *(const float4*)&embW[(size_t)clr1*1024 + U*4];
        } else {
          b0 = *(const float4*)&biasC[(l*256+U)*4];
          b1 = b0;
        }
        const int o0 = kh*2;
        float co0 = cS[pv0*128 + u], co1 = cS[pv1*128 + u];
        float gi0 = acc2[o0*2+0].x + p0.x + b0.x;
        float gf0 = acc2[o0*2+0].y + p0.y + b0.y;
        float gg0 = acc2[o0*2+1].x + p0.z + b0.z;
        float go0 = acc2[o0*2+1].y + p0.w + b0.w;
        float cn0 = sigf(gf0)*co0 + sigf(gi0)*tanhf(gg0);
        float hn0 = sigf(go0)*tanhf(cn0);
        float gi1 = acc2[(o0+1)*2+0].x + p1.x + b1.x;
        float gf1 = acc2[(o0+1)*2+0].y + p1.y + b1.y;
        float gg1 = acc2[(o0+1)*2+1].x + p1.z + b1.z;
        float go1 = acc2[(o0+1)*2+1].y + p1.w + b1.w;
        float cn1 = sigf(gf1)*co1 + sigf(gi1)*tanhf(gg1);
        float hn1 = sigf(go1)*tanhf(cn1);
        creg[l][0] = cn0; creg[l][1] = cn1;
        hS[l*2048 + or0*256 + U] = hn0;
        hS[l*2048 + or1*256 + U] = hn1;
        if (l == 2){
          float xv = x[(size_t)tn*32768 + smp*256 + U];
          st[or0*256 + U] = hn0 + xv;
          st[or1*256 + U] = hn1 + xv;
        }
        float* xm = xbase + (half*4 + (l+1))*1024;
        astoref(&xm[or0*128 + u], hn0);
        astoref(&xm[or1*128 + u], hn1);
      }
      __syncthreads();   // drains vmcnt: h exchange data at MALL before flag
      if (tid==0)
        __hip_atomic_store(&fme[(l+1)*2], (unsigned)(t+2), __ATOMIC_RELAXED, __HIP_MEMORY_SCOPE_AGENT);
    }
  }

  // ---- backtrace choices + prefix (half 0 only; both halves are identical) ----
  if (half==0 && tid < 8){
    int e = tid;
    for (int tt=63; tt>=0; --tt){
      out[(size_t)(smp*8+tid)*64 + tt] = (float)clsH[tt*8+e];
      e = (int)prevH[tt*8+e];
    }
    out[65536 + smp*8 + tid] = pfx[tid];
  }
}

extern "C" void kernel_launch(void* const* d_in, const int* in_sizes, int n_in,
                              void* d_out, int out_size, void* d_ws, size_t ws_size,
                              hipStream_t stream)
{
  const float* x   = (const float*)d_in[0];
  const float* emb = (const float*)d_in[1];
  const float* Wih = (const float*)d_in[2];
  const float* Whh = (const float*)d_in[3];
  const float* bih = (const float*)d_in[4];
  const float* bhh = (const float*)d_in[5];
  const float* Wp  = (const float*)d_in[6];
  const float* bp  = (const float*)d_in[7];
  float* ws = (float*)d_ws;

  float* embW  = ws + O_EMBW;
  float* WpT   = ws + O_WPT;
  float* wihT  = ws + O_WIHT;
  float* whhT  = ws + O_WHHT;
  float* biasC = ws + O_BIASC;
  float* xchg  = ws + O_XCHG;
  unsigned* flags = (unsigned*)(ws + O_FLAGS);

  k_prep<<<256,256,0,stream>>>(Wih,Whh,Wp,bih,bhh,wihT,whhT,WpT,biasC, ws + O_FLAGS);
  k_embW<<<256,256,0,stream>>>(emb, wihT, bih, bhh, embW);
  k_decode<<<256,512,0,stream>>>(x, WpT, wihT, whhT, biasC, embW, bp, xchg, flags, (float*)d_out);
}

// Round 4
// 4277.629 us; speedup vs baseline: 1.4683x; 1.3066x over previous
//
#include <hip/hip_runtime.h>
#include <math.h>

// T=64, B=128, H=256, C=256, K=8, L=3.
// Structure: 2 blocks per sample (unit-half split), 256 blocks, 512 threads.
// BISECT ROUND: R2/R3 failed identically (=> shared bug in {gemm8, proj-split}).
// This kernel = round-1 passing lineage + ONLY the LSTM gemm8 change:
//   thread map u=tid&127, kq=tid>>7; each thread computes ALL 8 beam rows x
//   4 gates of unit U over its 64-k quarter -> every LSTM W byte read ONCE
//   per block (2.5MB/step, was 5.0MB). Partial reduction: 3-round static
//   XOR-tree via LDS (A1/A2 pair tid^256, B pair tid^128), all acc2 indices
//   compile-time, branches wave-uniform on kq. Ownership or0=2*kq.
// Proj: REVERTED to round-1's exact version (2 rows x full 256k per thread,
// rq=tid>>7; W reads 4x) -- isolates the proj-split as the other suspect.
// Pair-sync: relaxed agent-scope atomics + monotonic flags (no acquire/release
// so L2 weight residency survives); writer: data -> __syncthreads (vmcnt
// drain) -> tid0 posts flag; reader: tid0 polls -> barrier -> loads. Flags
// zeroed by k_prep each launch (graph-replay safe).
static constexpr size_t O_EMBW  = 0;         // [256 cls][1024 (u*4+g)]  emb@Wih0^T + b0
static constexpr size_t O_WPT   = 262144;    // [256 k][256 c]
static constexpr size_t O_WIHT  = 327680;    // [3][256 k][1024 (u*4+g)]
static constexpr size_t O_WHHT  = 1114112;   // [3][256 k][1024 (u*4+g)]
static constexpr size_t O_BIASC = 1900544;   // [3][256 u][4 g]  bih+bhh
static constexpr size_t O_XCHG  = 1903616;   // [128 smp][2 half][4 phase][1024] floats
static constexpr size_t O_FLAGS = 2952192;   // 1024 uint32: [smp][4 phase][2 half]
// total 2953216 floats ≈ 11.8 MB

typedef float f2 __attribute__((ext_vector_type(2)));
__device__ __forceinline__ f2 fma2(f2 a, f2 b, f2 c){ return __builtin_elementwise_fma(a,b,c); }
__device__ __forceinline__ float sigf(float x){ return 1.0f/(1.0f + expf(-x)); }

__device__ __forceinline__ void astoref(float* p, float v){
  __hip_atomic_store(p, v, __ATOMIC_RELAXED, __HIP_MEMORY_SCOPE_AGENT);
}
__device__ __forceinline__ float aloadf(const float* p){
  return __hip_atomic_load((float*)p, __ATOMIC_RELAXED, __HIP_MEMORY_SCOPE_AGENT);
}

// ---------------- one-time prep: transposes + combined biases + flag reset ----
__global__ __launch_bounds__(256) void k_prep(
    const float* __restrict__ Wih, const float* __restrict__ Whh,
    const float* __restrict__ Wp,  const float* __restrict__ bih,
    const float* __restrict__ bhh,
    float* __restrict__ wihT, float* __restrict__ whhT,
    float* __restrict__ WpT, float* __restrict__ biasC,
    float* __restrict__ flagsF)
{
  const int NT = 786432;
  const int TOTAL = 2*NT + 65536 + 3072 + 1024;
  int stride = gridDim.x * blockDim.x;
  for (int i = blockIdx.x*blockDim.x + threadIdx.x; i < TOTAL; i += stride){
    if (i < NT){
      int l = i / 262144, r = i % 262144;      // r = row*256 + k
      int row = r >> 8, k = r & 255;
      int g = row >> 8, uu = row & 255;
      wihT[(size_t)l*262144 + (k<<10) + (uu<<2) + g] = Wih[i];
    } else if (i < 2*NT){
      int j = i - NT;
      int l = j / 262144, r = j % 262144;
      int row = r >> 8, k = r & 255;
      int g = row >> 8, uu = row & 255;
      whhT[(size_t)l*262144 + (k<<10) + (uu<<2) + g] = Whh[j];
    } else if (i < 2*NT + 65536){
      int j = i - 2*NT; int c = j >> 8, k = j & 255;
      WpT[(k<<8) + c] = Wp[j];
    } else if (i < 2*NT + 65536 + 3072){
      int j = i - 2*NT - 65536;          // [3][256][4]
      int l = j >> 10; int cg = j & 1023, uu = cg >> 2, g = cg & 3;
      biasC[j] = bih[l*1024 + g*256 + uu] + bhh[l*1024 + g*256 + uu];
    } else {
      flagsF[i - (2*NT + 65536 + 3072)] = 0.0f;   // zero sync flags every launch
    }
  }
}

// ------------- one-time: embW[cls][u*4+g] = emb@Wih0^T + bih0 + bhh0 ---------
__global__ __launch_bounds__(256) void k_embW(
    const float* __restrict__ emb, const float* __restrict__ wih0T,
    const float* __restrict__ bih, const float* __restrict__ bhh,
    float* __restrict__ embW)
{
  const int cls = blockIdx.x, uu = threadIdx.x;
  const float* er = emb + cls*256;
  float a0=0.f,a1=0.f,a2=0.f,a3=0.f;
  for (int k=0;k<256;k++){
    float ev = er[k];
    float4 w = *(const float4*)&wih0T[k*1024 + uu*4];
    a0 = fmaf(ev, w.x, a0); a1 = fmaf(ev, w.y, a1);
    a2 = fmaf(ev, w.z, a2); a3 = fmaf(ev, w.w, a3);
  }
  a0 += bih[uu]       + bhh[uu];
  a1 += bih[256+uu]   + bhh[256+uu];
  a2 += bih[512+uu]   + bhh[512+uu];
  a3 += bih[768+uu]   + bhh[768+uu];
  *(float4*)&embW[cls*1024 + uu*4] = make_float4(a0,a1,a2,a3);
}

// ---------------- decode: 2 blocks = 1 sample, 512 threads each --------------
__global__
__attribute__((amdgpu_flat_work_group_size(512,512)))
void k_decode(
    const float* __restrict__ x,      // [64][128][256]
    const float* __restrict__ WpT,    // [256 k][256 c]
    const float* __restrict__ wihT,   // [3][256 k][1024]
    const float* __restrict__ whhT,   // [3][256 k][1024]
    const float* __restrict__ biasC,  // [3][256 u][4 g]
    const float* __restrict__ embW,   // [256 cls][1024]
    const float* __restrict__ bp,     // [256]
    float* __restrict__ xchg,         // [128][2][4][1024]
    unsigned* __restrict__ flags,     // [128][4][2]
    float* __restrict__ out)
{
  __shared__ float hS[3*2048];   // h[l][row][unit 0..255] FULL width   24 KB
  __shared__ float cS[1024];     // staged c_old[row][own-unit 0..127]   4 KB
  __shared__ float st[2048];     // state[row][unit] FULL width          8 KB
  __shared__ float jnt[6144];    // logits / reduction slots (512x12)   24 KB
  __shared__ float pfx[8];
  __shared__ float red[8];  __shared__ int redi[8];
  __shared__ float sVal[8]; __shared__ int sPrev[8], sCls[8];
  __shared__ short prevH[512], clsH[512];

  const int tid  = threadIdx.x;
  const int bid  = blockIdx.x;
  const int half = (bid & 7) >> 2;          // 0: XCD 0-3, 1: XCD 4-7 (heuristic)
  const int oh   = half ^ 1;
  const int smp  = ((bid >> 3) << 2) | (bid & 3);   // sample 0..127, bijective
  const int u    = tid & 127;               // local unit / class col
  const int kq   = tid >> 7;                // k-quarter 0..3 (LSTM split-K)
  const int U    = (half << 7) | u;         // global unit / class
  const int or0  = kq*2;                    // owned beam rows (epilogue)
  const int or1  = or0 + 1;
  const int wv   = tid >> 6, lane = tid & 63;

  float* xbase = xchg + (size_t)smp*8192;
  unsigned* fme = flags + smp*8 + half;     // use fme[p*2]
  unsigned* fpr = flags + smp*8 + oh;

  float creg[3][2];                         // c for owned rows or0/or1, unit u
  const float bpc = bp[U];

  // ---- init: x0 into jnt[2048..2303]; st = x0 broadcast; prefix ----
  if (tid < 64) *(float4*)&jnt[2048 + tid*4] = *(const float4*)&x[(size_t)smp*256 + tid*4];
  if (tid < 8)  pfx[tid] = (tid==0) ? 0.0f : -1e30f;
  __syncthreads();
  *(float4*)&st[tid*4] = *(const float4*)&jnt[2048 + (tid&63)*4];

  // ---- init LSTM from zero state (M=1); per layer: compute own half, exchange
  for (int l=0; l<3; l++){
    if (tid < 128){
      const float* Wg = wihT + (size_t)l*262144;
      float a0=0.f,a1=0.f,a2=0.f,a3=0.f;
      for (int kc=0; kc<256; kc+=4){
        float4 a4 = *(const float4*)&jnt[2048+kc];
        float4 w0 = *(const float4*)&Wg[(size_t)(kc+0)*1024 + U*4];
        float4 w1 = *(const float4*)&Wg[(size_t)(kc+1)*1024 + U*4];
        float4 w2 = *(const float4*)&Wg[(size_t)(kc+2)*1024 + U*4];
        float4 w3 = *(const float4*)&Wg[(size_t)(kc+3)*1024 + U*4];
        a0=fmaf(a4.x,w0.x,a0); a0=fmaf(a4.y,w1.x,a0); a0=fmaf(a4.z,w2.x,a0); a0=fmaf(a4.w,w3.x,a0);
        a1=fmaf(a4.x,w0.y,a1); a1=fmaf(a4.y,w1.y,a1); a1=fmaf(a4.z,w2.y,a1); a1=fmaf(a4.w,w3.y,a1);
        a2=fmaf(a4.x,w0.z,a2); a2=fmaf(a4.y,w1.z,a2); a2=fmaf(a4.z,w2.z,a2); a2=fmaf(a4.w,w3.z,a2);
        a3=fmaf(a4.x,w0.w,a3); a3=fmaf(a4.y,w1.w,a3); a3=fmaf(a4.z,w2.w,a3); a3=fmaf(a4.w,w3.w,a3);
      }
      float4 bs = *(const float4*)&biasC[(l*256+U)*4];
      float gi=a0+bs.x, gg=a2+bs.z, go=a3+bs.w;  // c_old=0
      float cn = sigf(gi)*tanhf(gg);
      float hn = sigf(go)*tanhf(cn);
      jnt[tid] = hn; jnt[128+tid] = cn;
    }
    __syncthreads();
    {
      float* xm = xbase + (half*4 + (l+1))*1024;
      float hv = jnt[u], cv = jnt[128+u];
      creg[l][0] = cv; creg[l][1] = cv;
      hS[l*2048 + or0*256 + U] = hv;
      hS[l*2048 + or1*256 + U] = hv;
      astoref(&xm[or0*128 + u], hv);
      astoref(&xm[or1*128 + u], hv);
    }
    __syncthreads();   // drains vmcnt: exchange data at MALL
    if (tid==0){
      __hip_atomic_store(&fme[(l+1)*2], 1u, __ATOMIC_RELAXED, __HIP_MEMORY_SCOPE_AGENT);
      while (__hip_atomic_load(&fpr[(l+1)*2], __ATOMIC_RELAXED, __HIP_MEMORY_SCOPE_AGENT) < 1u)
        __builtin_amdgcn_s_sleep(2);
    }
    __syncthreads();
    {
      const float* xr = xbase + (oh*4 + (l+1))*1024;
      int r = tid>>6, u2 = (tid&63)*2;
      float v0 = aloadf(&xr[r*128+u2]);
      float v1 = aloadf(&xr[r*128+u2+1]);
      hS[l*2048 + r*256 + (oh<<7)+u2]   = v0;
      hS[l*2048 + r*256 + (oh<<7)+u2+1] = v1;
      if (l<2 && r==0){ jnt[2048+(oh<<7)+u2] = v0; jnt[2048+(oh<<7)+u2+1] = v1; }
    }
    if (l<2 && tid<128) jnt[2048 + U] = jnt[tid];   // own half of next input row
    __syncthreads();
  }

  // split-K GEMM: ALL 8 rows x 4 gate-cols of unit U over this thread's 64 k's.
  // 2-stage rolling W prefetch (32 VGPR). acc2: row i -> acc2[i*2]={g_i,g_f},
  // acc2[i*2+1]={g_g,g_o}. Every W byte read ONCE per block.
  auto gemm8 = [&](const float* hbaseK, const int* ro, const float* WgK, f2* acc2){
    const float* Wr = WgK + (U<<2);
    float4 wst[2][4];
    #pragma unroll
    for (int s=0; s<2; s++){
      const float* Wn = Wr + (size_t)(s*4)*1024;
      wst[s][0]=*(const float4*)&Wn[0];    wst[s][1]=*(const float4*)&Wn[1024];
      wst[s][2]=*(const float4*)&Wn[2048]; wst[s][3]=*(const float4*)&Wn[3072];
    }
    auto macblk = [&](const float4 wk[4], const float4 a[8]){
      #pragma unroll
      for (int kk=0;kk<4;kk++){
        f2 wlo = {wk[kk].x, wk[kk].y};
        f2 whi = {wk[kk].z, wk[kk].w};
        const float av4[8] = {
          kk==0?a[0].x:(kk==1?a[0].y:(kk==2?a[0].z:a[0].w)),
          kk==0?a[1].x:(kk==1?a[1].y:(kk==2?a[1].z:a[1].w)),
          kk==0?a[2].x:(kk==1?a[2].y:(kk==2?a[2].z:a[2].w)),
          kk==0?a[3].x:(kk==1?a[3].y:(kk==2?a[3].z:a[3].w)),
          kk==0?a[4].x:(kk==1?a[4].y:(kk==2?a[4].z:a[4].w)),
          kk==0?a[5].x:(kk==1?a[5].y:(kk==2?a[5].z:a[5].w)),
          kk==0?a[6].x:(kk==1?a[6].y:(kk==2?a[6].z:a[6].w)),
          kk==0?a[7].x:(kk==1?a[7].y:(kk==2?a[7].z:a[7].w))};
        #pragma unroll
        for (int i=0;i<8;i++){
          f2 av = {av4[i], av4[i]};
          acc2[i*2+0] = fma2(av, wlo, acc2[i*2+0]);
          acc2[i*2+1] = fma2(av, whi, acc2[i*2+1]);
        }
      }
    };
    #pragma unroll 1
    for (int kc=0; kc<56; kc+=8){             // consume k 0..55, refill to 63
      #pragma unroll
      for (int s=0; s<2; s++){
        const int kcur = kc + s*4;
        const float4 wk[4] = {wst[s][0], wst[s][1], wst[s][2], wst[s][3]};
        const float* Wn = Wr + (size_t)(kcur+8)*1024;
        wst[s][0]=*(const float4*)&Wn[0];    wst[s][1]=*(const float4*)&Wn[1024];
        wst[s][2]=*(const float4*)&Wn[2048]; wst[s][3]=*(const float4*)&Wn[3072];
        float4 a[8];
        #pragma unroll
        for (int i=0;i<8;i++) a[i] = *(const float4*)&hbaseK[ro[i] + kcur];
        macblk(wk, a);
      }
    }
    #pragma unroll
    for (int s=0; s<2; s++){                  // tail: k=56..63, no refill
      const int kcur = 56 + s*4;
      const float4 wk[4] = {wst[s][0], wst[s][1], wst[s][2], wst[s][3]};
      float4 a[8];
      #pragma unroll
      for (int i=0;i<8;i++) a[i] = *(const float4*)&hbaseK[ro[i] + kcur];
      macblk(wk, a);
    }
  };

  const int kqb = kq << 6;                  // this thread's 64-k base

  // ---------------- 64 decode steps ----------------
  for (int t=0; t<64; t++){
    // ---- phase3 poll: partner h[2] (+ partner half of st for t>0) ----
    if (tid==0){
      unsigned want = (unsigned)(t+1);
      while (__hip_atomic_load(&fpr[3*2], __ATOMIC_RELAXED, __HIP_MEMORY_SCOPE_AGENT) < want)
        __builtin_amdgcn_s_sleep(2);
    }
    __syncthreads();
    {
      const float* xr = xbase + (oh*4 + 3)*1024;
      int r = tid>>6, u2 = (tid&63)*2;
      float v0 = aloadf(&xr[r*128+u2]);
      float v1 = aloadf(&xr[r*128+u2+1]);
      hS[2*2048 + r*256 + (oh<<7)+u2]   = v0;
      hS[2*2048 + r*256 + (oh<<7)+u2+1] = v1;
      if (t > 0){
        f2 xv = *(const f2*)&x[(size_t)t*32768 + smp*256 + (oh<<7)+u2];
        st[r*256 + (oh<<7)+u2]   = v0 + xv.x;
        st[r*256 + (oh<<7)+u2+1] = v1 + xv.y;
      }
    }
    __syncthreads();   // st/hS[2] complete

    // ---- proj (ROUND-1 VERBATIM): rows rq*2, rq*2+1, own class col U;
    // full 256-k per thread, 4-stage scalar W prefetch. ----
    {
      const int rq = tid >> 7;                 // 0..3
      const float* A0 = st + (rq*2)*256;
      const float* A1 = st + (rq*2+1)*256;
      const float* Wc = WpT + U;
      f2 q01 = {0.f,0.f};
      float wstp[4][4];
      #pragma unroll
      for (int s=0;s<4;s++){
        #pragma unroll
        for (int q=0;q<4;q++) wstp[s][q] = Wc[(s*4+q)*256];
      }
      #pragma unroll 1
      for (int kc=0; kc<240; kc+=16){
        #pragma unroll
        for (int s=0;s<4;s++){
          const int kcur = kc + s*4;
          float w0=wstp[s][0], w1=wstp[s][1], w2=wstp[s][2], w3=wstp[s][3];
          #pragma unroll
          for (int q=0;q<4;q++) wstp[s][q] = Wc[(kcur+16+q)*256];
          float4 a0 = *(const float4*)&A0[kcur];
          float4 a1 = *(const float4*)&A1[kcur];
          q01 = fma2((f2){a0.x,a1.x}, (f2){w0,w0}, q01);
          q01 = fma2((f2){a0.y,a1.y}, (f2){w1,w1}, q01);
          q01 = fma2((f2){a0.z,a1.z}, (f2){w2,w2}, q01);
          q01 = fma2((f2){a0.w,a1.w}, (f2){w3,w3}, q01);
        }
      }
      #pragma unroll
      for (int s=0;s<4;s++){
        const int kcur = 240 + s*4;
        float w0=wstp[s][0], w1=wstp[s][1], w2=wstp[s][2], w3=wstp[s][3];
        float4 a0 = *(const float4*)&A0[kcur];
        float4 a1 = *(const float4*)&A1[kcur];
        q01 = fma2((f2){a0.x,a1.x}, (f2){w0,w0}, q01);
        q01 = fma2((f2){a0.y,a1.y}, (f2){w1,w1}, q01);
        q01 = fma2((f2){a0.z,a1.z}, (f2){w2,w2}, q01);
        q01 = fma2((f2){a0.w,a1.w}, (f2){w3,w3}, q01);
      }
      float v0 = q01.x + bpc, v1 = q01.y + bpc;
      float* xm = xbase + (half*4 + 0)*1024;
      jnt[(rq*2)*256 + U]   = v0;
      jnt[(rq*2+1)*256 + U] = v1;
      astoref(&xm[(rq*2)*128 + u],   v0);
      astoref(&xm[(rq*2+1)*128 + u], v1);
    }
    __syncthreads();   // jnt own half visible; exchange data at MALL
    if (tid==0){
      __hip_atomic_store(&fme[0], (unsigned)(t+1), __ATOMIC_RELAXED, __HIP_MEMORY_SCOPE_AGENT);
      while (__hip_atomic_load(&fpr[0], __ATOMIC_RELAXED, __HIP_MEMORY_SCOPE_AGENT) < (unsigned)(t+1))
        __builtin_amdgcn_s_sleep(2);
    }
    __syncthreads();
    {
      const float* xr = xbase + (oh*4 + 0)*1024;
      int r = tid>>6, c2 = (tid&63)*2;
      jnt[r*256 + (oh<<7) + c2]   = aloadf(&xr[r*128+c2]);
      jnt[r*256 + (oh<<7) + c2+1] = aloadf(&xr[r*128+c2+1]);
    }
    __syncthreads();

    // ---- log-softmax + prefix: wave wv handles beam-row wv (redundant x2) ----
    {
      const int kb = wv;
      float4 v = *(const float4*)&jnt[kb*256 + lane*4];
      float m = fmaxf(fmaxf(v.x,v.y),fmaxf(v.z,v.w));
      for (int off=32;off;off>>=1) m = fmaxf(m, __shfl_down(m,off));
      m = __shfl(m, 0);
      double s = exp((double)v.x-(double)m)+exp((double)v.y-(double)m)
               + exp((double)v.z-(double)m)+exp((double)v.w-(double)m);
      for (int off=32;off;off>>=1) s += __shfl_down(s,off);
      s = __shfl(s, 0);
      double lse = log(s);
      float pf = pfx[kb];
      float4 o;
      o.x = (float)((double)v.x - (double)m - lse) + pf;
      o.y = (float)((double)v.y - (double)m - lse) + pf;
      o.z = (float)((double)v.z - (double)m - lse) + pf;
      o.w = (float)((double)v.w - (double)m - lse) + pf;
      *(float4*)&jnt[kb*256+lane*4] = o;
    }
    __syncthreads();

    // ---- top-8 of joint[2048]; stride-512 reads, (val, lowest-idx) ----
    for (int r=0;r<8;r++){
      float bv = -INFINITY; int bi = 0;
      #pragma unroll
      for (int i=0;i<4;i++){
        int idx = tid + 512*i; float vv = jnt[idx];
        if (vv > bv){ bv=vv; bi=idx; }
      }
      for (int off=32;off;off>>=1){
        float ov = __shfl_down(bv,off); int oi = __shfl_down(bi,off);
        if (ov>bv || (ov==bv && oi<bi)){ bv=ov; bi=oi; }
      }
      if (lane==0){ red[wv]=bv; redi[wv]=bi; }
      __syncthreads();
      if (tid==0){
        float BV=red[0]; int BI=redi[0];
        for (int j=1;j<8;j++) if (red[j]>BV || (red[j]==BV && redi[j]<BI)){BV=red[j];BI=redi[j];}
        sVal[r]=BV; sPrev[r]=BI>>8; sCls[r]=BI&255;
        jnt[BI] = -INFINITY;
      }
      __syncthreads();
    }
    if (tid<8){
      pfx[tid] = sVal[tid];
      prevH[t*8+tid] = (short)sPrev[tid];
      clsH[t*8+tid]  = (short)sCls[tid];
    }
    __syncthreads();

    int rog8[8], rod8[8];
    #pragma unroll
    for (int r=0;r<8;r++){ rog8[r] = sPrev[r]*256; rod8[r] = r*256; }
    const int clr0 = sCls[or0], clr1 = sCls[or1];
    const int pv0  = sPrev[or0], pv1 = sPrev[or1];

    // ---- 3 LSTM layers (unit-split across pair, 4-way split-K in block) ----
    #pragma unroll 1
    for (int l=0; l<3; l++){
      cS[or0*128 + u] = creg[l][0];
      cS[or1*128 + u] = creg[l][1];
      __syncthreads();   // cS visible; hS stable; jnt free

      f2 acc2[16];
      #pragma unroll
      for (int i=0;i<16;i++) acc2[i] = (f2){0.f,0.f};
      // recurrent first (operands resident) -> hides the h[l-1] exchange poll
      gemm8(hS + l*2048 + kqb, rog8,
            whhT + (size_t)l*262144 + (size_t)kqb*1024, acc2);
      if (l > 0){
        if (tid==0){
          unsigned want = (unsigned)(t+2);
          while (__hip_atomic_load(&fpr[l*2], __ATOMIC_RELAXED, __HIP_MEMORY_SCOPE_AGENT) < want)
            __builtin_amdgcn_s_sleep(2);
        }
        __syncthreads();
        {
          const float* xr = xbase + (oh*4 + l)*1024;
          int r = tid>>6, u2 = (tid&63)*2;
          hS[(l-1)*2048 + r*256 + (oh<<7)+u2]   = aloadf(&xr[r*128+u2]);
          hS[(l-1)*2048 + r*256 + (oh<<7)+u2+1] = aloadf(&xr[r*128+u2+1]);
        }
        __syncthreads();
        gemm8(hS + (l-1)*2048 + kqb, rod8,
              wihT + (size_t)l*262144 + (size_t)kqb*1024, acc2);
      }

      // ---- 3-round static XOR-tree reduction (slots: jnt[tid*12], 8 floats) --
      // A1/A2: partner tid^256 (kq^2). kq<2 keeps rows 0-3, kq>=2 keeps 4-7.
      // B: partner tid^128 (kq^1). Final: rows or0=2kq, or1 in G0..G3.
      f2 G0, G1, G2, G3;
      {
        const int dA = (tid ^ 256) * 12;
        const int dB = (tid ^ 128) * 12;
        float4 p0, p1, r0, r1;
        // A1: ship rows {4,5} (kq<2) / {0,1} (kq>=2)
        if (kq < 2){
          p0 = make_float4(acc2[8].x, acc2[8].y, acc2[9].x, acc2[9].y);
          p1 = make_float4(acc2[10].x,acc2[10].y,acc2[11].x,acc2[11].y);
        } else {
          p0 = make_float4(acc2[0].x, acc2[0].y, acc2[1].x, acc2[1].y);
          p1 = make_float4(acc2[2].x, acc2[2].y, acc2[3].x, acc2[3].y);
        }
        *(float4*)&jnt[dA] = p0; *(float4*)&jnt[dA+4] = p1;
        __syncthreads();
        r0 = *(const float4*)&jnt[tid*12];
        r1 = *(const float4*)&jnt[tid*12+4];
        if (kq < 2){
          acc2[0] += (f2){r0.x,r0.y}; acc2[1] += (f2){r0.z,r0.w};
          acc2[2] += (f2){r1.x,r1.y}; acc2[3] += (f2){r1.z,r1.w};
        } else {
          acc2[0] = acc2[8]  + (f2){r0.x,r0.y}; acc2[1] = acc2[9]  + (f2){r0.z,r0.w};
          acc2[2] = acc2[10] + (f2){r1.x,r1.y}; acc2[3] = acc2[11] + (f2){r1.z,r1.w};
        }
        __syncthreads();   // slot reuse
        // A2: ship rows {6,7} (kq<2) / {2,3} (kq>=2)
        if (kq < 2){
          p0 = make_float4(acc2[12].x,acc2[12].y,acc2[13].x,acc2[13].y);
          p1 = make_float4(acc2[14].x,acc2[14].y,acc2[15].x,acc2[15].y);
        } else {
          p0 = make_float4(acc2[4].x, acc2[4].y, acc2[5].x, acc2[5].y);
          p1 = make_float4(acc2[6].x, acc2[6].y, acc2[7].x, acc2[7].y);
        }
        *(float4*)&jnt[dA] = p0; *(float4*)&jnt[dA+4] = p1;
        __syncthreads();
        r0 = *(const float4*)&jnt[tid*12];
        r1 = *(const float4*)&jnt[tid*12+4];
        if (kq < 2){
          acc2[4] += (f2){r0.x,r0.y}; acc2[5] += (f2){r0.z,r0.w};
          acc2[6] += (f2){r1.x,r1.y}; acc2[7] += (f2){r1.z,r1.w};
        } else {
          acc2[4] = acc2[12] + (f2){r0.x,r0.y}; acc2[5] = acc2[13] + (f2){r0.z,r0.w};
          acc2[6] = acc2[14] + (f2){r1.x,r1.y}; acc2[7] = acc2[15] + (f2){r1.z,r1.w};
        }
        __syncthreads();   // slot reuse
        // B: ship the non-owned row pair; keep the owned pair.
        if (kq & 1){
          p0 = make_float4(acc2[0].x, acc2[0].y, acc2[1].x, acc2[1].y);
          p1 = make_float4(acc2[2].x, acc2[2].y, acc2[3].x, acc2[3].y);
        } else {
          p0 = make_float4(acc2[4].x, acc2[4].y, acc2[5].x, acc2[5].y);
          p1 = make_float4(acc2[6].x, acc2[6].y, acc2[7].x, acc2[7].y);
        }
        *(float4*)&jnt[dB] = p0; *(float4*)&jnt[dB+4] = p1;
        __syncthreads();
        r0 = *(const float4*)&jnt[tid*12];
        r1 = *(const float4*)&jnt[tid*12+4];
        f2 k0, k1, k2, k3;
        if (kq & 1){ k0=acc2[4]; k1=acc2[5]; k2=acc2[6]; k3=acc2[7]; }
        else       { k0=acc2[0]; k1=acc2[1]; k2=acc2[2]; k3=acc2[3]; }
        G0 = k0 + (f2){r0.x,r0.y};   // row or0 {i,f}
        G1 = k1 + (f2){r0.z,r0.w};   // row or0 {g,o}
        G2 = k2 + (f2){r1.x,r1.y};   // row or1 {i,f}
        G3 = k3 + (f2){r1.z,r1.w};   // row or1 {g,o}
      }

      // ---- cell epilogue: every thread finalizes its rows or0, or1 ----
      {
        const int tn = (t < 63) ? (t+1) : 63;
        float4 b0, b1;
        if (l==0){
          b0 = *(const float4*)&embW[(size_t)clr0*1024 + U*4];
          b1 = *(const float4*)&embW[(size_t)clr1*1024 + U*4];
        } else {
          b0 = *(const float4*)&biasC[(l*256+U)*4];
          b1 = b0;
        }
        float co0 = cS[pv0*128 + u], co1 = cS[pv1*128 + u];
        float gi0 = G0.x + b0.x, gf0 = G0.y + b0.y;
        float gg0 = G1.x + b0.z, go0 = G1.y + b0.w;
        float cn0 = sigf(gf0)*co0 + sigf(gi0)*tanhf(gg0);
        float hn0 = sigf(go0)*tanhf(cn0);
        float gi1 = G2.x + b1.x, gf1 = G2.y + b1.y;
        float gg1 = G3.x + b1.z, go1 = G3.y + b1.w;
        float cn1 = sigf(gf1)*co1 + sigf(gi1)*tanhf(gg1);
        float hn1 = sigf(go1)*tanhf(cn1);
        creg[l][0] = cn0; creg[l][1] = cn1;
        hS[l*2048 + or0*256 + U] = hn0;
        hS[l*2048 + or1*256 + U] = hn1;
        if (l == 2){
          float xv = x[(size_t)tn*32768 + smp*256 + U];
          st[or0*256 + U] = hn0 + xv;
          st[or1*256 + U] = hn1 + xv;
        }
        float* xm = xbase + (half*4 + (l+1))*1024;
        astoref(&xm[or0*128 + u], hn0);
        astoref(&xm[or1*128 + u], hn1);
      }
      __syncthreads();   // drains vmcnt: h exchange data at MALL before flag
      if (tid==0)
        __hip_atomic_store(&fme[(l+1)*2], (unsigned)(t+2), __ATOMIC_RELAXED, __HIP_MEMORY_SCOPE_AGENT);
    }
  }

  // ---- backtrace choices + prefix (half 0 only; both halves identical) ----
  if (half==0 && tid < 8){
    int e = tid;
    for (int tt=63; tt>=0; --tt){
      out[(size_t)(smp*8+tid)*64 + tt] = (float)clsH[tt*8+e];
      e = (int)prevH[tt*8+e];
    }
    out[65536 + smp*8 + tid] = pfx[tid];
  }
}

extern "C" void kernel_launch(void* const* d_in, const int* in_sizes, int n_in,
                              void* d_out, int out_size, void* d_ws, size_t ws_size,
                              hipStream_t stream)
{
  const float* x   = (const float*)d_in[0];
  const float* emb = (const float*)d_in[1];
  const float* Wih = (const float*)d_in[2];
  const float* Whh = (const float*)d_in[3];
  const float* bih = (const float*)d_in[4];
  const float* bhh = (const float*)d_in[5];
  const float* Wp  = (const float*)d_in[6];
  const float* bp  = (const float*)d_in[7];
  float* ws = (float*)d_ws;

  float* embW  = ws + O_EMBW;
  float* WpT   = ws + O_WPT;
  float* wihT  = ws + O_WIHT;
  float* whhT  = ws + O_WHHT;
  float* biasC = ws + O_BIASC;
  float* xchg  = ws + O_XCHG;
  unsigned* flags = (unsigned*)(ws + O_FLAGS);

  k_prep<<<256,256,0,stream>>>(Wih,Whh,Wp,bih,bhh,wihT,whhT,WpT,biasC, ws + O_FLAGS);
  k_embW<<<256,256,0,stream>>>(emb, wihT, bih, bhh, embW);
  k_decode<<<256,512,0,stream>>>(x, WpT, wihT, whhT, biasC, embW, bp, xchg, flags, (float*)d_out);
}